// Round 1
// 131.922 us; speedup vs baseline: 1.0344x; 1.0344x over previous
//
#include <hip/hip_runtime.h>

// VQ-VAE vector quantizer, MI355X gfx950 — round 5: K2+K3 fused.
//  K1 prep : W fp32 -> bf16 (wbf) + ||w||^2 (wn) + zero accumulators
//  K2 fused: per-64-row block: stage z (kept in 64 VGPRs for the loss),
//            bf16 MFMA scores with depth-3 counted-vmcnt pipeline (T3/T4/T5),
//            in-block argmin -> LDS, DMA-gather W rows (conflict-free s>>2
//            granule rotation), transposed write of z_q + fused MSE losses.
// z is read from HBM exactly once; z_q written once; W lives in L2.

#define DIM      256
#define NCODES   1024
#define SPB      1024
#define ZQ_ELEMS 8388608
#define NBLK     512       // 32768 rows / 64

typedef float f32x4  __attribute__((ext_vector_type(4)));
typedef short bf16x8 __attribute__((ext_vector_type(8)));
typedef short bf16x4 __attribute__((ext_vector_type(4)));

__device__ __forceinline__ short f2bf(float f) {
    union { float f; unsigned u; } v; v.f = f;
    unsigned r = v.u + 0x7FFFu + ((v.u >> 16) & 1u);   // RNE
    return (short)(r >> 16);
}

#define GLL16(g, l)                                                            \
    __builtin_amdgcn_global_load_lds(                                          \
        (const __attribute__((address_space(1))) void*)(g),                    \
        (__attribute__((address_space(3))) void*)(l), 16, 0, 0)

#define WAITV(n)  asm volatile("s_waitcnt vmcnt(" #n ")" ::: "memory")
#define WAITLGKM  asm volatile("s_waitcnt lgkmcnt(0)" ::: "memory")

// ---------------- K1: prep ----------------
__global__ __launch_bounds__(256) void prep(const float* __restrict__ w,
                                            short* __restrict__ wbf,
                                            float* __restrict__ wn,
                                            float* __restrict__ acc,
                                            unsigned* __restrict__ done) {
    const int t = threadIdx.x, wv = t >> 6, l = t & 63;
    const int k = blockIdx.x * 4 + wv;          // one wave per code
    const float* wr = w + (size_t)k * DIM + 4 * l;
    f32x4 v = *(const f32x4*)wr;
    bf16x4 p;
    p[0] = f2bf(v[0]); p[1] = f2bf(v[1]); p[2] = f2bf(v[2]); p[3] = f2bf(v[3]);
    *(bf16x4*)(wbf + (size_t)k * DIM + 4 * l) = p;
    float s = v[0]*v[0] + v[1]*v[1] + v[2]*v[2] + v[3]*v[3];
#pragma unroll
    for (int off = 32; off; off >>= 1) s += __shfl_down(s, off);
    if (l == 0) wn[k] = s;
    if (blockIdx.x == 0 && t == 0) { *acc = 0.f; *done = 0u; }
}

// ---------------- K2: fused gemm+argmin+gather+loss ----------------
// LDS union region smem[0..66560):
//   phase 1-2: zs fp32 [256 c][65]            (66560 B)
//   phase 3  : wb bf16 4 tiles x 16384 B      (65536 B, depth-3 pipeline)
//   phase 5-6: zql fp32 64 rows x 1 KB        (65536 B)
// fixed: wnl fp32[1024] @66560, sidx int[64] @70656, wsum f32[4] @70912
__global__ __launch_bounds__(256, 2) void vq_fused(const float* __restrict__ z,
                                                   const short* __restrict__ wbf,
                                                   const float* __restrict__ wn,
                                                   const float* __restrict__ w,
                                                   float* __restrict__ out,
                                                   float* __restrict__ acc,
                                                   unsigned* __restrict__ done) {
    __shared__ __align__(16) char smem[70928];
    float* zs   = (float*)smem;
    float* zql  = (float*)smem;
    float* wnl  = (float*)(smem + 66560);
    int*   sidx = (int*)  (smem + 70656);
    float* wsum = (float*)(smem + 70912);

    const int t   = threadIdx.x;
    const int wv  = t >> 6;
    const int l   = t & 63;
    const int n16 = l & 15;
    const int q   = l >> 4;
    const int sx  = t & 15;      // s-window: this thread owns s = 4*sx .. 4*sx+3
    const int c0  = t >> 4;      // channel group: c = c0 + 16*ci

    const int n0    = blockIdx.x * 64;
    const int batch = n0 >> 10;
    const int sbase = n0 & 1023;
    const float* zb = z   + (size_t)batch * DIM * SPB + sbase;
    float*       ob = out + (size_t)batch * DIM * SPB + sbase;

    // ---- phase 1: z -> regs (kept for the loss) + LDS transpose, wn -> LDS
    f32x4 v[16];
#pragma unroll
    for (int ci = 0; ci < 16; ++ci)
        v[ci] = *(const f32x4*)(zb + (size_t)(c0 + 16 * ci) * SPB + 4 * sx);
#pragma unroll
    for (int ci = 0; ci < 16; ++ci)
        *(f32x4*)&zs[65 * (c0 + 16 * ci) + 4 * sx] = v[ci];
    *(f32x4*)&wnl[4 * t] = *(const f32x4*)(wn + 4 * t);
    __syncthreads();

    // ---- phase 2: A fragments, row m = 16*wv + n16, d = 32T + 8q + j
    bf16x8 af[8];
#pragma unroll
    for (int T = 0; T < 8; ++T) {
        bf16x8 a;
#pragma unroll
        for (int j = 0; j < 8; ++j)
            a[j] = f2bf(zs[65 * (32 * T + 8 * q + j) + 16 * wv + n16]);
        af[T] = a;
    }
    __syncthreads();   // zs dead; wb region may now be overwritten

    // ---- B staging offsets: 32-code tile, granule-XOR swizzle (proven)
    int soff[4];
#pragma unroll
    for (int i = 0; i < 4; ++i) {
        int G = i * 256 + t;
        int n = G >> 5, p = G & 31;
        soff[i] = n * 256 + 8 * (p ^ (n & 7));
    }
    int offT[8];
#pragma unroll
    for (int T = 0; T < 8; ++T) offT[T] = ((4 * T + q) ^ (n16 & 7)) * 16;

    // ---- prologue: issue tiles 0,1,2 (depth-3)
#pragma unroll
    for (int pt = 0; pt < 3; ++pt) {
        const short* gb = wbf + (size_t)pt * 32 * DIM;
        char* db = smem + pt * 16384;
#pragma unroll
        for (int i = 0; i < 4; ++i) GLL16(gb + soff[i], db + (i * 256 + t) * 16);
    }

    float best[4];
    int   bidx[4];
#pragma unroll
    for (int r = 0; r < 4; ++r) { best[r] = 3.4e38f; bidx[r] = 0; }

    // ---- main loop: counted vmcnt, raw barriers (T3+T4), setprio (T5)
    for (int kt = 0; kt < 32; ++kt) {
        if (kt <= 28) {
            const short* gb = wbf + (size_t)(kt + 3) * 32 * DIM;
            char* db = smem + ((kt + 3) & 3) * 16384;
#pragma unroll
            for (int i = 0; i < 4; ++i)
                GLL16(gb + soff[i], db + (i * 256 + t) * 16);
            WAITV(12);               // tile kt landed; kt+1..kt+3 in flight
        } else if (kt == 29) { WAITV(8); }
        else if (kt == 30)   { WAITV(4); }
        else                 { WAITV(0); }
        __builtin_amdgcn_s_barrier();

        const int k0 = kt * 32 + n16;
        const float w0 = wnl[k0];
        const float w1 = wnl[k0 + 16];

        const char* wp = smem + (kt & 3) * 16384;
        f32x4 a0 = {0.f, 0.f, 0.f, 0.f};
        f32x4 a1 = {0.f, 0.f, 0.f, 0.f};
        __builtin_amdgcn_s_setprio(1);
#pragma unroll
        for (int T = 0; T < 8; ++T) {
            bf16x8 b0 = *(const bf16x8*)(wp + (0 * 16 + n16) * 512 + offT[T]);
            bf16x8 b1 = *(const bf16x8*)(wp + (1 * 16 + n16) * 512 + offT[T]);
            a0 = __builtin_amdgcn_mfma_f32_16x16x32_bf16(af[T], b0, a0, 0, 0, 0);
            a1 = __builtin_amdgcn_mfma_f32_16x16x32_bf16(af[T], b1, a1, 0, 0, 0);
        }
        __builtin_amdgcn_s_setprio(0);
#pragma unroll
        for (int r = 0; r < 4; ++r) {
            float d0 = w0 - 2.f * a0[r];
            if (d0 < best[r]) { best[r] = d0; bidx[r] = k0; }
            float d1 = w1 - 2.f * a1[r];
            if (d1 < best[r]) { best[r] = d1; bidx[r] = k0 + 16; }
        }
        WAITLGKM;                    // all ds_reads of this buf retired
        __builtin_amdgcn_s_barrier();// before next iter's DMA overwrites it
    }

    // ---- phase 4: cross-lane argmin over 16 code lanes; row m = 16wv+4q+r
#pragma unroll
    for (int r = 0; r < 4; ++r) {
        float bv = best[r];
        int   bi = bidx[r];
#pragma unroll
        for (int m = 1; m < 16; m <<= 1) {
            float ov = __shfl_xor(bv, m);
            int   oi = __shfl_xor(bi, m);
            if (ov < bv || (ov == bv && oi < bi)) { bv = ov; bi = oi; }
        }
        if (n16 == 0) sidx[16 * wv + 4 * q + r] = bi;
    }
    __syncthreads();

    // ---- phase 5: DMA-gather selected code rows, rotated by (s>>2) granules
    // logical dword c of row s lands at phys dword (c + 4*(s>>2)) & 255
    int ks[16];
#pragma unroll
    for (int i = 0; i < 16; ++i) ks[i] = sidx[16 * wv + i];
#pragma unroll
    for (int i = 0; i < 16; ++i) {
        const int s = 16 * wv + i;
        const float* src = w + (size_t)ks[i] * DIM + 4 * ((l - (s >> 2)) & 63);
        GLL16(src, (char*)smem + s * 1024 + l * 16);
    }
    WAITV(0);
    __syncthreads();

    // ---- phase 6: transposed z_q write + fused losses (z from regs)
    // read bank = (c0 + 4*sx + const)&31 -> 32 banks, 2 lanes each = free
    float lsum = 0.f;
#pragma unroll
    for (int ci = 0; ci < 16; ++ci) {
        const int c = c0 + 16 * ci;
        f32x4 qv;
#pragma unroll
        for (int r = 0; r < 4; ++r)
            qv[r] = zql[(4 * sx + r) * 256 + ((c + 4 * sx) & 255)];
        __builtin_nontemporal_store(qv, (f32x4*)(ob + (size_t)c * SPB + 4 * sx));
        f32x4 d = v[ci] - qv;
        lsum += d[0]*d[0] + d[1]*d[1] + d[2]*d[2] + d[3]*d[3];
    }

#pragma unroll
    for (int off = 32; off; off >>= 1) lsum += __shfl_down(lsum, off);
    if (l == 0) wsum[wv] = lsum;
    __syncthreads();
    if (t == 0) {
        atomicAdd(acc, wsum[0] + wsum[1] + wsum[2] + wsum[3]);
        __threadfence();
        unsigned prev = atomicAdd(done, 1u);
        if (prev == NBLK - 1) {
            float val = atomicAdd(acc, 0.f) * (1.f / 8388608.f);
            out[ZQ_ELEMS]     = val;
            out[ZQ_ELEMS + 1] = val;
        }
    }
}

extern "C" void kernel_launch(void* const* d_in, const int* in_sizes, int n_in,
                              void* d_out, int out_size, void* d_ws, size_t ws_size,
                              hipStream_t stream) {
    const float* z = (const float*)d_in[0];
    const float* w = (const float*)d_in[1];
    float* out = (float*)d_out;

    char* ws = (char*)d_ws;
    short*    wbf  = (short*)ws;                   // 512 KB
    float*    wn   = (float*)(ws + 524288);        // 4 KB
    float*    acc  = (float*)(ws + 528384);
    unsigned* done = (unsigned*)(ws + 528388);

    prep<<<256, 256, 0, stream>>>(w, wbf, wn, acc, done);
    vq_fused<<<NBLK, 256, 0, stream>>>(z, wbf, wn, w, out, acc, done);
}